// Round 1
// baseline (2128.447 us; speedup 1.0000x reference)
//
#include <hip/hip_runtime.h>
#include <hip/hip_cooperative_groups.h>

namespace cg = cooperative_groups;

#define N 4096
#define D 64
#define TAILM 512
#define NBLK 256
#define NTHR 512
#define GRIDT (NBLK * NTHR)

typedef unsigned long long u64;

// ---- persistent device state (avoids any dependence on ws_size) ----
__device__ float g_C[(size_t)N * (size_t)N];   // 64 MB cost matrix
__device__ float g_tailC[TAILM * TAILM];       // 1 MB dense tail matrix
__device__ float g_x2[N], g_y2[N];
__device__ int   g_rowMatch[N];
__device__ int   g_freeRows[2][N];
__device__ int   g_freeCols[2][N];
__device__ int   g_rowBestJ[N];
__device__ u64   g_colMin[2][N];
__device__ int   g_nr[2], g_nc[2];

__device__ inline u64 shfl_down_u64(u64 v, int d) {
  unsigned lo = (unsigned)(v & 0xffffffffull);
  unsigned hi = (unsigned)(v >> 32);
  lo = __shfl_down(lo, d, 64);
  hi = __shfl_down(hi, d, 64);
  return ((u64)hi << 32) | (u64)lo;
}

// 512-thread block min-reduce of per-thread best[r] (r < rows <= 16).
// Result for row r left in s_part[128 + r], written by thread r itself.
__device__ inline void block_rowmin_reduce(u64* best, int rows, u64* s_part) {
  const int tid = threadIdx.x;
  const int lane = tid & 63;
  const int wv = tid >> 6;
#pragma unroll
  for (int r = 0; r < 16; ++r) {
    if (r < rows) {
      u64 v = best[r];
#pragma unroll
      for (int d = 32; d > 0; d >>= 1) {
        u64 o = shfl_down_u64(v, d);
        v = (o < v) ? o : v;
      }
      if (lane == 0) s_part[r * 8 + wv] = v;
    }
  }
  __syncthreads();
  if (tid < rows) {
    u64 mn = s_part[tid * 8];
#pragma unroll
    for (int w = 1; w < 8; ++w) {
      u64 o = s_part[tid * 8 + w];
      mn = (o < mn) ? o : mn;
    }
    s_part[128 + tid] = mn;
  }
}

__global__ void __launch_bounds__(NTHR, 2) greedy_match_kernel(
    const float* __restrict__ x, const float* __restrict__ y, int* __restrict__ out) {
  __shared__ u64 s_colPart[4096];
  __shared__ u64 s_part[128 + 16];
  __shared__ u64 s_cmin[TAILM];
  __shared__ int s_ftr[2][TAILM];
  __shared__ int s_ftc[2][TAILM];
  __shared__ int s_rbTC[TAILM];
  __shared__ int s_irow[16];
  __shared__ float s_x2r[16];
  __shared__ int s_wc[8];
  __shared__ int s_base;

  const int tid = threadIdx.x;
  const int bid = blockIdx.x;
  const int gix = bid * NTHR + tid;
  cg::grid_group grid = cg::this_grid();

  // ================= phase 0: init =================
  for (int i = gix; i < N; i += GRIDT) {
    // numpy pairwise_sum order for n=64: 8 accumulators, then
    // ((r0+r1)+(r2+r3)) + ((r4+r5)+(r6+r7)). No FMA contraction.
    const float* xr = x + (size_t)i * D;
    const float* yr = y + (size_t)i * D;
    float qx[8], qy[8];
#pragma unroll
    for (int j = 0; j < 8; ++j) {
      float v = xr[j]; qx[j] = __fmul_rn(v, v);
      float w = yr[j]; qy[j] = __fmul_rn(w, w);
    }
#pragma unroll
    for (int m = 8; m < D; m += 8) {
#pragma unroll
      for (int j = 0; j < 8; ++j) {
        float v = xr[m + j]; qx[j] = __fadd_rn(qx[j], __fmul_rn(v, v));
        float w = yr[m + j]; qy[j] = __fadd_rn(qy[j], __fmul_rn(w, w));
      }
    }
    g_x2[i] = __fadd_rn(__fadd_rn(__fadd_rn(qx[0], qx[1]), __fadd_rn(qx[2], qx[3])),
                        __fadd_rn(__fadd_rn(qx[4], qx[5]), __fadd_rn(qx[6], qx[7])));
    g_y2[i] = __fadd_rn(__fadd_rn(__fadd_rn(qy[0], qy[1]), __fadd_rn(qy[2], qy[3])),
                        __fadd_rn(__fadd_rn(qy[4], qy[5]), __fadd_rn(qy[6], qy[7])));
    g_rowMatch[i] = -1;
    g_freeRows[0][i] = i;
    g_freeCols[0][i] = i;
    g_colMin[0][i] = ~0ull;
    g_colMin[1][i] = ~0ull;
  }
  if (gix == 0) { g_nr[0] = N; g_nc[0] = N; g_nr[1] = 0; g_nc[1] = 0; }
  grid.sync();

  // ================= main (grid-wide) rounds =================
  int cur = 0, buf = 0;
  int nr = N, nc = N;
  bool toTail = false;

  for (int round = 0; round < 4096; ++round) {
    // ---------- SCAN ----------
    {
      const int ngroups = (nr + 15) >> 4;
      if (bid < ngroups) {
        const int r0 = bid << 4;
        const int rows = min(16, nr - r0);
        if (tid < 16) {
          int rr = (tid < rows) ? (r0 + tid) : r0;
          int i = g_freeRows[cur][rr];
          s_irow[tid] = i;
          s_x2r[tid] = g_x2[i];
        }
        for (int c = tid; c < nc; c += NTHR) s_colPart[c] = ~0ull;  // thread-owned slots
        __syncthreads();

        int ir[16];
        float x2r[16];
#pragma unroll
        for (int r = 0; r < 16; ++r) {
          ir[r] = __builtin_amdgcn_readfirstlane(s_irow[r]);
          x2r[r] = __uint_as_float((unsigned)__builtin_amdgcn_readfirstlane((int)__float_as_uint(s_x2r[r])));
        }
        u64 best[16];
#pragma unroll
        for (int r = 0; r < 16; ++r) best[r] = ~0ull;

        if (round == 0) {
          // fused: compute cost (exact fp32 order), store C, update mins
          for (int c = tid; c < nc; c += NTHR) {
            const int j = c;  // round-0 free-col list is identity
            const float y2j = g_y2[j];
            const float4* yy = reinterpret_cast<const float4*>(y + (size_t)j * D);
            float acc[16];
#pragma unroll
            for (int r = 0; r < 16; ++r) acc[r] = 0.0f;
#pragma unroll
            for (int kc = 0; kc < 16; ++kc) {
              float4 yv = yy[kc];
#pragma unroll
              for (int r = 0; r < 16; ++r) {
                if (r < rows) {
                  const float4* xb = reinterpret_cast<const float4*>(x + (size_t)ir[r] * D);
                  float4 xv = xb[kc];
                  acc[r] = fmaf(xv.x, yv.x, acc[r]);
                  acc[r] = fmaf(xv.y, yv.y, acc[r]);
                  acc[r] = fmaf(xv.z, yv.z, acc[r]);
                  acc[r] = fmaf(xv.w, yv.w, acc[r]);
                }
              }
            }
            u64 cpart = s_colPart[c];
#pragma unroll
            for (int r = 0; r < 16; ++r) {
              if (r < rows) {
                float t = __fadd_rn(x2r[r], y2j);
                float sq = __fsub_rn(t, __fmul_rn(2.0f, acc[r]));
                sq = fmaxf(sq, 0.0f);
                float cost = __fsqrt_rn(sq);
                g_C[(size_t)ir[r] * N + j] = cost;
                u64 cb = ((u64)__float_as_uint(cost)) << 32;
                u64 rk = cb | (unsigned)j;
                best[r] = (rk < best[r]) ? rk : best[r];
                u64 ck = cb | (unsigned)ir[r];
                cpart = (ck < cpart) ? ck : cpart;
              }
            }
            s_colPart[c] = cpart;
          }
        } else {
          for (int c = tid; c < nc; c += NTHR) {
            const int j = g_freeCols[cur][c];
            u64 cpart = s_colPart[c];
#pragma unroll
            for (int r = 0; r < 16; ++r) {
              if (r < rows) {
                float cost = g_C[(size_t)ir[r] * N + j];
                u64 cb = ((u64)__float_as_uint(cost)) << 32;
                u64 rk = cb | (unsigned)j;
                best[r] = (rk < best[r]) ? rk : best[r];
                u64 ck = cb | (unsigned)ir[r];
                cpart = (ck < cpart) ? ck : cpart;
              }
            }
            s_colPart[c] = cpart;
          }
        }

        block_rowmin_reduce(best, rows, s_part);
        if (tid < rows) {
          g_rowBestJ[s_irow[tid]] = (int)(s_part[128 + tid] & 0xffffffffull);
        }
        // flush col partials (same thread owns same slots -> no sync needed)
        for (int c = tid; c < nc; c += NTHR) {
          u64 k = s_colPart[c];
          if (k != ~0ull) {
            int j = (round == 0) ? c : g_freeCols[cur][c];
            u64 curv = g_colMin[buf][j];  // stale reads only ever too-high: safe filter
            if (k < curv) atomicMin(&g_colMin[buf][j], k);
          }
        }
      }
    }
    grid.sync();

    // ---------- MATCH / REBUILD ----------
    {
      for (int t = gix; t < N; t += GRIDT) g_colMin[buf ^ 1][t] = ~0ull;  // reset next buffer

      if (bid == 0) {  // rows: write matches + ordered compaction
        if (tid == 0) s_base = 0;
        __syncthreads();
        for (int start = 0; start < nr; start += NTHR) {
          int r = start + tid;
          int keep = 0; int iv = -1;
          if (r < nr) {
            int i = g_freeRows[cur][r];
            iv = i;
            int j = g_rowBestJ[i];
            u64 cm = g_colMin[buf][j];
            if ((int)(unsigned)(cm & 0xffffffffull) == i) g_rowMatch[i] = j;
            else keep = 1;
          }
          u64 bm = __ballot(keep);
          int lane = tid & 63, wv = tid >> 6;
          int pre = __popcll(bm & ((1ull << lane) - 1ull));
          if (lane == 0) s_wc[wv] = __popcll(bm);
          __syncthreads();
          int off = 0, tot = 0;
#pragma unroll
          for (int w = 0; w < 8; ++w) { off += (w < wv) ? s_wc[w] : 0; tot += s_wc[w]; }
          if (keep) g_freeRows[cur ^ 1][s_base + off + pre] = iv;
          __syncthreads();
          if (tid == 0) s_base += tot;
          __syncthreads();
        }
        if (tid == 0) g_nr[cur ^ 1] = s_base;
      } else if (bid == 1) {  // cols
        if (tid == 0) s_base = 0;
        __syncthreads();
        for (int start = 0; start < nc; start += NTHR) {
          int c = start + tid;
          int keep = 0; int jv = -1;
          if (c < nc) {
            int j = g_freeCols[cur][c];
            jv = j;
            u64 cm = g_colMin[buf][j];
            int i2 = (int)(unsigned)(cm & 0xffffffffull);
            if (g_rowBestJ[i2] != j) keep = 1;
          }
          u64 bm = __ballot(keep);
          int lane = tid & 63, wv = tid >> 6;
          int pre = __popcll(bm & ((1ull << lane) - 1ull));
          if (lane == 0) s_wc[wv] = __popcll(bm);
          __syncthreads();
          int off = 0, tot = 0;
#pragma unroll
          for (int w = 0; w < 8; ++w) { off += (w < wv) ? s_wc[w] : 0; tot += s_wc[w]; }
          if (keep) g_freeCols[cur ^ 1][s_base + off + pre] = jv;
          __syncthreads();
          if (tid == 0) s_base += tot;
          __syncthreads();
        }
        if (tid == 0) g_nc[cur ^ 1] = s_base;
      }
    }
    grid.sync();

    volatile int* vnr = g_nr;
    volatile int* vnc = g_nc;
    int nnr = vnr[cur ^ 1];
    int nnc = vnc[cur ^ 1];
    if (nnr <= 0) break;
    if (nnr >= nr) break;  // safety: no progress (cannot happen mathematically)
    cur ^= 1; buf ^= 1; nr = nnr; nc = nnc;
    if (nr <= TAILM) { toTail = true; break; }
  }

  // ================= tail: dense matrix, single block, no grid syncs =================
  if (toTail) {
    for (int r = bid; r < nr; r += NBLK) {
      int i = g_freeRows[cur][r];
      const float* crow = g_C + (size_t)i * N;
      for (int c = tid; c < nc; c += NTHR) {
        g_tailC[r * TAILM + c] = crow[g_freeCols[cur][c]];
      }
    }
    grid.sync();
    if (bid == 0) {
      const int m = nr;
      for (int t = tid; t < m; t += NTHR) { s_ftr[0][t] = t; s_ftc[0][t] = t; }
      __syncthreads();
      int tcur = 0, mr = m, mc = m;
      for (int tround = 0; tround < 1024 && mr > 0; ++tround) {
        for (int c = tid; c < mc; c += NTHR) s_colPart[c] = ~0ull;  // thread-owned
        const int ngr = (mr + 15) >> 4;
        for (int g = 0; g < ngr; ++g) {
          const int rows = min(16, mr - (g << 4));
          int tr16[16];
#pragma unroll
          for (int r = 0; r < 16; ++r) {
            int rr = (r < rows) ? ((g << 4) + r) : (g << 4);
            tr16[r] = s_ftr[tcur][rr];
          }
          u64 best[16];
#pragma unroll
          for (int r = 0; r < 16; ++r) best[r] = ~0ull;
          for (int c = tid; c < mc; c += NTHR) {
            int tc = s_ftc[tcur][c];
            u64 cpart = s_colPart[c];
#pragma unroll
            for (int r = 0; r < 16; ++r) {
              if (r < rows) {
                float cost = g_tailC[tr16[r] * TAILM + tc];
                u64 cb = ((u64)__float_as_uint(cost)) << 32;
                u64 rk = cb | (unsigned)tc;  // lists stay sorted => tail-idx order == orig order
                best[r] = (rk < best[r]) ? rk : best[r];
                u64 ck = cb | (unsigned)tr16[r];
                cpart = (ck < cpart) ? ck : cpart;
              }
            }
            s_colPart[c] = cpart;
          }
          block_rowmin_reduce(best, rows, s_part);
          if (tid < rows) {
            s_rbTC[s_ftr[tcur][(g << 4) + tid]] = (int)(s_part[128 + tid] & 0xffffffffull);
          }
          __syncthreads();
        }
        // materialize col-mins indexed by tail-col id
        for (int c = tid; c < mc; c += NTHR) s_cmin[s_ftc[tcur][c]] = s_colPart[c];
        __syncthreads();
        // rows: match + compact (single chunk, mr <= 512)
        int keep = 0, trv = -1;
        if (tid < mr) {
          int tr = s_ftr[tcur][tid]; trv = tr;
          int tc = s_rbTC[tr];
          if ((int)(unsigned)(s_cmin[tc] & 0xffffffffull) == tr) {
            g_rowMatch[g_freeRows[cur][tr]] = g_freeCols[cur][tc];
          } else keep = 1;
        }
        u64 bm = __ballot(keep);
        int lane = tid & 63, wv = tid >> 6;
        int pre = __popcll(bm & ((1ull << lane) - 1ull));
        if (lane == 0) s_wc[wv] = __popcll(bm);
        __syncthreads();
        int off = 0, tot = 0;
#pragma unroll
        for (int w = 0; w < 8; ++w) { off += (w < wv) ? s_wc[w] : 0; tot += s_wc[w]; }
        if (keep) s_ftr[tcur ^ 1][off + pre] = trv;
        int newmr = tot;
        __syncthreads();
        // cols: compact
        int keepc = 0, tcv = -1;
        if (tid < mc) {
          int tc = s_ftc[tcur][tid]; tcv = tc;
          int tr2 = (int)(unsigned)(s_cmin[tc] & 0xffffffffull);
          if (s_rbTC[tr2] != tc) keepc = 1;
        }
        u64 bm2 = __ballot(keepc);
        int pre2 = __popcll(bm2 & ((1ull << lane) - 1ull));
        if (lane == 0) s_wc[wv] = __popcll(bm2);
        __syncthreads();
        int off2 = 0, tot2 = 0;
#pragma unroll
        for (int w = 0; w < 8; ++w) { off2 += (w < wv) ? s_wc[w] : 0; tot2 += s_wc[w]; }
        if (keepc) s_ftc[tcur ^ 1][off2 + pre2] = tcv;
        __syncthreads();
        if (newmr >= mr) break;  // safety
        mr = newmr; mc = tot2; tcur ^= 1;
      }
    }
  }

  grid.sync();
  for (int i = gix; i < N; i += GRIDT) out[i] = g_rowMatch[i];
}

extern "C" void kernel_launch(void* const* d_in, const int* in_sizes, int n_in,
                              void* d_out, int out_size, void* d_ws, size_t ws_size,
                              hipStream_t stream) {
  const float* x = (const float*)d_in[0];
  const float* y = (const float*)d_in[1];
  int* out = (int*)d_out;
  void* args[] = { (void*)&x, (void*)&y, (void*)&out };
  hipLaunchCooperativeKernel((void*)greedy_match_kernel, dim3(NBLK), dim3(NTHR), args, 0, stream);
  (void)in_sizes; (void)n_in; (void)out_size; (void)d_ws; (void)ws_size;
}

// Round 2
// 1987.258 us; speedup vs baseline: 1.0710x; 1.0710x over previous
//
#include <hip/hip_runtime.h>

#define N 4096
#define D 64
#define TTAIL 512
#define TCAP 1024
#define SNB 256
#define SNT 512
#define RPAIRS 10

typedef unsigned long long u64;

// ---- persistent device state ----
__device__ float g_C[(size_t)N * (size_t)N];   // 64 MB cost matrix
__device__ float g_x2[N], g_y2[N];
__device__ int   g_rowMatch[N];
__device__ int   g_freeRows[2][N];
__device__ int   g_freeCols[2][N];
__device__ int   g_rowBestJ[N];
__device__ u64   g_colMin[2][N];
__device__ int   g_nr[2], g_nc[2];
__device__ int   g_done, g_finalCur;

__device__ inline u64 shfl_down_u64(u64 v, int d) {
  unsigned lo = (unsigned)(v & 0xffffffffull);
  unsigned hi = (unsigned)(v >> 32);
  lo = __shfl_down(lo, d, 64);
  hi = __shfl_down(hi, d, 64);
  return ((u64)hi << 32) | (u64)lo;
}

// 512-thread (8-wave) block min-reduce of per-thread best[r], r < rows <= 16.
// Result for row r in s_part[128 + r].
__device__ inline void block_rowmin_reduce8(u64* best, int rows, u64* s_part) {
  const int tid = threadIdx.x;
  const int lane = tid & 63;
  const int wv = tid >> 6;
#pragma unroll
  for (int r = 0; r < 16; ++r) {
    if (r < rows) {
      u64 v = best[r];
#pragma unroll
      for (int d = 32; d > 0; d >>= 1) {
        u64 o = shfl_down_u64(v, d);
        v = (o < v) ? o : v;
      }
      if (lane == 0) s_part[r * 8 + wv] = v;
    }
  }
  __syncthreads();
  if (tid < rows) {
    u64 mn = s_part[tid * 8];
#pragma unroll
    for (int w = 1; w < 8; ++w) {
      u64 o = s_part[tid * 8 + w];
      mn = (o < mn) ? o : mn;
    }
    s_part[128 + tid] = mn;
  }
}

// ================= init: x2/y2 + state reset =================
__global__ void __launch_bounds__(256) k_init(const float* __restrict__ x,
                                              const float* __restrict__ y) {
  const int i = blockIdx.x * 256 + threadIdx.x;  // grid = 16 blocks -> 4096
  // numpy pairwise_sum order for n=64: 8 accumulators, then
  // ((r0+r1)+(r2+r3)) + ((r4+r5)+(r6+r7)). No FMA contraction.
  const float* xr = x + (size_t)i * D;
  const float* yr = y + (size_t)i * D;
  float qx[8], qy[8];
#pragma unroll
  for (int j = 0; j < 8; ++j) {
    float v = xr[j]; qx[j] = __fmul_rn(v, v);
    float w = yr[j]; qy[j] = __fmul_rn(w, w);
  }
#pragma unroll
  for (int m = 8; m < D; m += 8) {
#pragma unroll
    for (int j = 0; j < 8; ++j) {
      float v = xr[m + j]; qx[j] = __fadd_rn(qx[j], __fmul_rn(v, v));
      float w = yr[m + j]; qy[j] = __fadd_rn(qy[j], __fmul_rn(w, w));
    }
  }
  g_x2[i] = __fadd_rn(__fadd_rn(__fadd_rn(qx[0], qx[1]), __fadd_rn(qx[2], qx[3])),
                      __fadd_rn(__fadd_rn(qx[4], qx[5]), __fadd_rn(qx[6], qx[7])));
  g_y2[i] = __fadd_rn(__fadd_rn(__fadd_rn(qy[0], qy[1]), __fadd_rn(qy[2], qy[3])),
                      __fadd_rn(__fadd_rn(qy[4], qy[5]), __fadd_rn(qy[6], qy[7])));
  g_rowMatch[i] = -1;
  g_freeRows[0][i] = i;
  g_freeCols[0][i] = i;
  g_colMin[0][i] = ~0ull;
  g_colMin[1][i] = ~0ull;
  if (i == 0) {
    g_nr[0] = N; g_nc[0] = N; g_nr[1] = 0; g_nc[1] = 0;
    g_done = 0;
    g_finalCur = ((RPAIRS & 1) ^ 1);  // fallback: parity of last match's output lists
  }
}

// ================= round 0: fused cost + C store + row/col minima =================
__global__ void __launch_bounds__(SNT, 2) k_scan0(const float* __restrict__ x,
                                                  const float* __restrict__ y) {
  __shared__ u64 s_colPart[4096];
  __shared__ u64 s_part[128 + 16];
  const int tid = threadIdx.x;
  const int bid = blockIdx.x;
  const int r0 = bid << 4;  // 256 blocks x 16 rows = 4096

  for (int c = tid; c < N; c += SNT) s_colPart[c] = ~0ull;  // thread-owned slots
  __syncthreads();

  float x2r[16];
#pragma unroll
  for (int r = 0; r < 16; ++r) x2r[r] = g_x2[r0 + r];
  u64 best[16];
#pragma unroll
  for (int r = 0; r < 16; ++r) best[r] = ~0ull;

  for (int c = tid; c < N; c += SNT) {
    const int j = c;
    const float y2j = g_y2[j];
    const float4* yy = reinterpret_cast<const float4*>(y + (size_t)j * D);
    float acc[16];
#pragma unroll
    for (int r = 0; r < 16; ++r) acc[r] = 0.0f;
#pragma unroll
    for (int kc = 0; kc < 16; ++kc) {
      float4 yv = yy[kc];
#pragma unroll
      for (int r = 0; r < 16; ++r) {
        const float4* xb = reinterpret_cast<const float4*>(x + (size_t)(r0 + r) * D);
        float4 xv = xb[kc];
        acc[r] = fmaf(xv.x, yv.x, acc[r]);
        acc[r] = fmaf(xv.y, yv.y, acc[r]);
        acc[r] = fmaf(xv.z, yv.z, acc[r]);
        acc[r] = fmaf(xv.w, yv.w, acc[r]);
      }
    }
    u64 cpart = s_colPart[c];
#pragma unroll
    for (int r = 0; r < 16; ++r) {
      float t = __fadd_rn(x2r[r], y2j);
      float sq = __fsub_rn(t, __fmul_rn(2.0f, acc[r]));
      sq = fmaxf(sq, 0.0f);
      float cost = __fsqrt_rn(sq);
      g_C[(size_t)(r0 + r) * N + j] = cost;
      u64 cb = ((u64)__float_as_uint(cost)) << 32;
      u64 rk = cb | (unsigned)j;
      best[r] = (rk < best[r]) ? rk : best[r];
      u64 ck = cb | (unsigned)(r0 + r);
      cpart = (ck < cpart) ? ck : cpart;
    }
    s_colPart[c] = cpart;
  }

  block_rowmin_reduce8(best, 16, s_part);
  if (tid < 16) g_rowBestJ[r0 + tid] = (int)(s_part[128 + tid] & 0xffffffffull);

  for (int c = tid; c < N; c += SNT) {
    u64 k = s_colPart[c];
    u64 curv = g_colMin[0][c];  // stale reads only ever too-high: safe filter
    if (k < curv) atomicMin((unsigned long long*)&g_colMin[0][c], k);
  }
}

// ================= rounds >= 1: gather scan over free rows/cols =================
__global__ void __launch_bounds__(SNT, 2) k_scanN(int round) {
  if (g_done) return;
  const int cur = round & 1;
  const int nr = g_nr[cur], nc = g_nc[cur];
  const int tid = threadIdx.x, bid = blockIdx.x;
  const int ngroups = (nr + 15) >> 4;
  if (bid >= ngroups) return;
  __shared__ u64 s_colPart[4096];
  __shared__ u64 s_part[128 + 16];
  __shared__ int s_irow[16];

  const int r0 = bid << 4;
  const int rows = min(16, nr - r0);
  if (tid < 16) {
    int rr = (tid < rows) ? (r0 + tid) : r0;
    s_irow[tid] = g_freeRows[cur][rr];
  }
  for (int c = tid; c < nc; c += SNT) s_colPart[c] = ~0ull;
  __syncthreads();

  int ir[16];
#pragma unroll
  for (int r = 0; r < 16; ++r) ir[r] = s_irow[r];
  u64 best[16];
#pragma unroll
  for (int r = 0; r < 16; ++r) best[r] = ~0ull;

  for (int c = tid; c < nc; c += SNT) {
    const int j = g_freeCols[cur][c];
    u64 cpart = s_colPart[c];
#pragma unroll
    for (int r = 0; r < 16; ++r) {
      if (r < rows) {
        float cost = g_C[(size_t)ir[r] * N + j];
        u64 cb = ((u64)__float_as_uint(cost)) << 32;
        u64 rk = cb | (unsigned)j;
        best[r] = (rk < best[r]) ? rk : best[r];
        u64 ck = cb | (unsigned)ir[r];
        cpart = (ck < cpart) ? ck : cpart;
      }
    }
    s_colPart[c] = cpart;
  }

  block_rowmin_reduce8(best, rows, s_part);
  if (tid < rows) g_rowBestJ[s_irow[tid]] = (int)(s_part[128 + tid] & 0xffffffffull);

  for (int c = tid; c < nc; c += SNT) {
    u64 k = s_colPart[c];
    if (k != ~0ull) {
      int j = g_freeCols[cur][c];
      u64 curv = g_colMin[cur][j];
      if (k < curv) atomicMin((unsigned long long*)&g_colMin[cur][j], k);
    }
  }
}

// ================= match + rebuild free lists =================
__global__ void __launch_bounds__(SNT) k_match(int round) {
  if (g_done) return;
  const int cur = round & 1, nxt = cur ^ 1;
  const int tid = threadIdx.x, bid = blockIdx.x;
  const int nr = g_nr[cur], nc = g_nc[cur];
  __shared__ int s_wc[8];
  __shared__ int s_base;

  if (bid >= 2) {  // reset colMin buffer for round+1
    for (int t = (bid - 2) * SNT + tid; t < N; t += (SNB - 2) * SNT)
      g_colMin[nxt][t] = ~0ull;
    return;
  }

  const int lane = tid & 63, wv = tid >> 6;
  if (bid == 0) {  // rows: write matches + ordered compaction
    if (tid == 0) s_base = 0;
    __syncthreads();
    for (int start = 0; start < nr; start += SNT) {
      int r = start + tid;
      int keep = 0; int iv = -1;
      if (r < nr) {
        int i = g_freeRows[cur][r];
        iv = i;
        int j = g_rowBestJ[i];
        u64 cm = g_colMin[cur][j];
        if ((int)(unsigned)(cm & 0xffffffffull) == i) g_rowMatch[i] = j;
        else keep = 1;
      }
      u64 bm = __ballot(keep);
      int pre = __popcll(bm & ((1ull << lane) - 1ull));
      if (lane == 0) s_wc[wv] = __popcll(bm);
      __syncthreads();
      int off = 0, tot = 0;
#pragma unroll
      for (int w = 0; w < 8; ++w) { off += (w < wv) ? s_wc[w] : 0; tot += s_wc[w]; }
      if (keep) g_freeRows[nxt][s_base + off + pre] = iv;
      __syncthreads();
      if (tid == 0) s_base += tot;
      __syncthreads();
    }
    if (tid == 0) {
      int nnr = s_base;
      g_nr[nxt] = nnr;
      if (nnr <= TTAIL || nnr >= nr) { g_finalCur = nxt; g_done = 1; }
    }
  } else {  // cols
    if (tid == 0) s_base = 0;
    __syncthreads();
    for (int start = 0; start < nc; start += SNT) {
      int c = start + tid;
      int keep = 0; int jv = -1;
      if (c < nc) {
        int j = g_freeCols[cur][c];
        jv = j;
        u64 cm = g_colMin[cur][j];
        int i2 = (int)(unsigned)(cm & 0xffffffffull);
        if (g_rowBestJ[i2] != j) keep = 1;
      }
      u64 bm = __ballot(keep);
      int pre = __popcll(bm & ((1ull << lane) - 1ull));
      if (lane == 0) s_wc[wv] = __popcll(bm);
      __syncthreads();
      int off = 0, tot = 0;
#pragma unroll
      for (int w = 0; w < 8; ++w) { off += (w < wv) ? s_wc[w] : 0; tot += s_wc[w]; }
      if (keep) g_freeCols[nxt][s_base + off + pre] = jv;
      __syncthreads();
      if (tid == 0) s_base += tot;
      __syncthreads();
    }
    if (tid == 0) g_nc[nxt] = s_base;
  }
}

// ================= tail: one block finishes all remaining rounds =================
__global__ void __launch_bounds__(1024, 1) k_tail(int* __restrict__ out) {
  __shared__ int s_rid[2][TCAP], s_cid[2][TCAP];
  __shared__ u64 s_colPart[TCAP];
  __shared__ u64 s_part[16 * 16];
  __shared__ int s_best[TCAP];
  __shared__ int s_wc[16];
  const int tid = threadIdx.x;
  const int lane = tid & 63, wv = tid >> 6;

  const int fc = g_finalCur;
  int mr = g_nr[fc], mc = g_nc[fc];
  if (mr < 0 || mr > TCAP || mc > TCAP) mr = 0;  // safety bail (shouldn't happen)
  for (int t = tid; t < mr; t += 1024) s_rid[0][t] = g_freeRows[fc][t];
  for (int t = tid; t < mc; t += 1024) s_cid[0][t] = g_freeCols[fc][t];
  __syncthreads();

  int tcur = 0;
  for (int round = 0; round < 2048 && mr > 0; ++round) {
    s_colPart[tid] = ~0ull;  // thread-owned slot (mc <= 1024 = blockDim)
    __syncthreads();
    const int jc = (tid < mc) ? s_cid[tcur][tid] : 0;
    const int ngr = (mr + 15) >> 4;
    for (int g = 0; g < ngr; ++g) {
      const int rbase = g << 4;
      const int rows = min(16, mr - rbase);
      u64 best[16];
#pragma unroll
      for (int r = 0; r < 16; ++r) best[r] = ~0ull;
      if (tid < mc) {
        u64 cpart = s_colPart[tid];
#pragma unroll
        for (int r = 0; r < 16; ++r) {
          if (r < rows) {
            int irow = s_rid[tcur][rbase + r];  // uniform
            float cost = g_C[(size_t)irow * N + jc];
            u64 cb = ((u64)__float_as_uint(cost)) << 32;
            u64 rk = cb | (unsigned)tid;          // col position (order-consistent)
            best[r] = (rk < best[r]) ? rk : best[r];
            u64 ck = cb | (unsigned)(rbase + r);  // row position
            cpart = (ck < cpart) ? ck : cpart;
          }
        }
        s_colPart[tid] = cpart;
      }
#pragma unroll
      for (int r = 0; r < 16; ++r) {
        if (r < rows) {
          u64 v = best[r];
#pragma unroll
          for (int d2 = 32; d2 > 0; d2 >>= 1) {
            u64 o = shfl_down_u64(v, d2);
            v = (o < v) ? o : v;
          }
          if (lane == 0) s_part[r * 16 + wv] = v;
        }
      }
      __syncthreads();
      if (tid < rows) {
        u64 mn = s_part[tid * 16];
#pragma unroll
        for (int w = 1; w < 16; ++w) { u64 o = s_part[tid * 16 + w]; mn = (o < mn) ? o : mn; }
        s_best[rbase + tid] = (int)(mn & 0xffffffffull);
      }
      __syncthreads();
    }
    // rows: match + compact
    int keep = 0;
    if (tid < mr) {
      int q = s_best[tid];
      if ((int)(unsigned)(s_colPart[q] & 0xffffffffull) == tid) {
        g_rowMatch[s_rid[tcur][tid]] = s_cid[tcur][q];
      } else keep = 1;
    }
    u64 bm = __ballot(keep);
    int pre = __popcll(bm & ((1ull << lane) - 1ull));
    if (lane == 0) s_wc[wv] = __popcll(bm);
    __syncthreads();
    int off = 0, tot = 0;
#pragma unroll
    for (int w = 0; w < 16; ++w) { off += (w < wv) ? s_wc[w] : 0; tot += s_wc[w]; }
    if (keep) s_rid[tcur ^ 1][off + pre] = s_rid[tcur][tid];
    int newmr = tot;
    __syncthreads();
    // cols: compact
    int keepc = 0;
    if (tid < mc) {
      int r2 = (int)(unsigned)(s_colPart[tid] & 0xffffffffull);
      if (s_best[r2] != tid) keepc = 1;
    }
    u64 bm2 = __ballot(keepc);
    int pre2 = __popcll(bm2 & ((1ull << lane) - 1ull));
    if (lane == 0) s_wc[wv] = __popcll(bm2);
    __syncthreads();
    int off2 = 0, tot2 = 0;
#pragma unroll
    for (int w = 0; w < 16; ++w) { off2 += (w < wv) ? s_wc[w] : 0; tot2 += s_wc[w]; }
    if (keepc) s_cid[tcur ^ 1][off2 + pre2] = s_cid[tcur][tid];
    __syncthreads();
    if (newmr >= mr) break;  // safety (cannot happen mathematically)
    mr = newmr; mc = tot2; tcur ^= 1;
  }
  __syncthreads();
  for (int i = tid; i < N; i += 1024) out[i] = g_rowMatch[i];
}

extern "C" void kernel_launch(void* const* d_in, const int* in_sizes, int n_in,
                              void* d_out, int out_size, void* d_ws, size_t ws_size,
                              hipStream_t stream) {
  const float* x = (const float*)d_in[0];
  const float* y = (const float*)d_in[1];
  int* out = (int*)d_out;
  k_init<<<16, 256, 0, stream>>>(x, y);
  k_scan0<<<SNB, SNT, 0, stream>>>(x, y);
  k_match<<<SNB, SNT, 0, stream>>>(0);
  for (int r = 1; r <= RPAIRS; ++r) {
    k_scanN<<<SNB, SNT, 0, stream>>>(r);
    k_match<<<SNB, SNT, 0, stream>>>(r);
  }
  k_tail<<<1, 1024, 0, stream>>>(out);
  (void)in_sizes; (void)n_in; (void)out_size; (void)d_ws; (void)ws_size;
}

// Round 4
// 1630.204 us; speedup vs baseline: 1.3056x; 1.2190x over previous
//
#include <hip/hip_runtime.h>

#define N 4096
#define D 64
#define TCAP 1024
#define SNB 256
#define SNT 512
#define RPAIRS 10

typedef unsigned long long u64;

// ---- persistent device state ----
__device__ float g_C[(size_t)N * (size_t)N];   // 64 MB cost matrix
__device__ float g_tailC[(size_t)TCAP * TCAP]; // 4 MB dense tail matrix
__device__ float g_x2[N], g_y2[N];
__device__ int   g_rowMatch[N];
__device__ int   g_freeRows[2][N];
__device__ int   g_freeCols[2][N];
__device__ int   g_rowBestJ[N];
__device__ u64   g_colMin[2][N];
__device__ int   g_nr[2], g_nc[2];
__device__ int   g_done, g_finalCur;

__device__ inline u64 shfl_down_u64(u64 v, int d) {
  unsigned lo = (unsigned)(v & 0xffffffffull);
  unsigned hi = (unsigned)(v >> 32);
  lo = __shfl_down(lo, d, 64);
  hi = __shfl_down(hi, d, 64);
  return ((u64)hi << 32) | (u64)lo;
}

// 512-thread (8-wave) block min-reduce of per-thread best[r], r < rows <= 16.
// Result for row r in s_part[128 + r].
__device__ inline void block_rowmin_reduce8(u64* best, int rows, u64* s_part) {
  const int tid = threadIdx.x;
  const int lane = tid & 63;
  const int wv = tid >> 6;
#pragma unroll
  for (int r = 0; r < 16; ++r) {
    if (r < rows) {
      u64 v = best[r];
#pragma unroll
      for (int d = 32; d > 0; d >>= 1) {
        u64 o = shfl_down_u64(v, d);
        v = (o < v) ? o : v;
      }
      if (lane == 0) s_part[r * 8 + wv] = v;
    }
  }
  __syncthreads();
  if (tid < rows) {
    u64 mn = s_part[tid * 8];
#pragma unroll
    for (int w = 1; w < 8; ++w) {
      u64 o = s_part[tid * 8 + w];
      mn = (o < mn) ? o : mn;
    }
    s_part[128 + tid] = mn;
  }
}

// ================= init: x2/y2 + state reset =================
__global__ void __launch_bounds__(256) k_init(const float* __restrict__ x,
                                              const float* __restrict__ y) {
  const int i = blockIdx.x * 256 + threadIdx.x;  // grid = 16 blocks -> 4096
  // numpy pairwise_sum order for n=64: 8 accumulators, then
  // ((r0+r1)+(r2+r3)) + ((r4+r5)+(r6+r7)). No FMA contraction.
  const float* xr = x + (size_t)i * D;
  const float* yr = y + (size_t)i * D;
  float qx[8], qy[8];
#pragma unroll
  for (int j = 0; j < 8; ++j) {
    float v = xr[j]; qx[j] = __fmul_rn(v, v);
    float w = yr[j]; qy[j] = __fmul_rn(w, w);
  }
#pragma unroll
  for (int m = 8; m < D; m += 8) {
#pragma unroll
    for (int j = 0; j < 8; ++j) {
      float v = xr[m + j]; qx[j] = __fadd_rn(qx[j], __fmul_rn(v, v));
      float w = yr[m + j]; qy[j] = __fadd_rn(qy[j], __fmul_rn(w, w));
    }
  }
  g_x2[i] = __fadd_rn(__fadd_rn(__fadd_rn(qx[0], qx[1]), __fadd_rn(qx[2], qx[3])),
                      __fadd_rn(__fadd_rn(qx[4], qx[5]), __fadd_rn(qx[6], qx[7])));
  g_y2[i] = __fadd_rn(__fadd_rn(__fadd_rn(qy[0], qy[1]), __fadd_rn(qy[2], qy[3])),
                      __fadd_rn(__fadd_rn(qy[4], qy[5]), __fadd_rn(qy[6], qy[7])));
  g_rowMatch[i] = -1;
  g_freeRows[0][i] = i;
  g_freeCols[0][i] = i;
  g_colMin[0][i] = ~0ull;
  g_colMin[1][i] = ~0ull;
  if (i == 0) {
    g_nr[0] = N; g_nc[0] = N; g_nr[1] = 0; g_nc[1] = 0;
    g_done = 0;
    g_finalCur = ((RPAIRS & 1) ^ 1);  // fallback parity if g_done never fires
  }
}

// ================= round 0: fused cost + C store + row/col minima =================
__global__ void __launch_bounds__(SNT, 2) k_scan0(const float* __restrict__ x,
                                                  const float* __restrict__ y) {
  __shared__ u64 s_colPart[4096];
  __shared__ u64 s_part[128 + 16];
  const int tid = threadIdx.x;
  const int bid = blockIdx.x;
  const int r0 = bid << 4;  // 256 blocks x 16 rows = 4096

  for (int c = tid; c < N; c += SNT) s_colPart[c] = ~0ull;  // thread-owned slots
  __syncthreads();

  float x2r[16];
#pragma unroll
  for (int r = 0; r < 16; ++r) x2r[r] = g_x2[r0 + r];
  u64 best[16];
#pragma unroll
  for (int r = 0; r < 16; ++r) best[r] = ~0ull;

  for (int c = tid; c < N; c += SNT) {
    const int j = c;
    const float y2j = g_y2[j];
    const float4* yy = reinterpret_cast<const float4*>(y + (size_t)j * D);
    float acc[16];
#pragma unroll
    for (int r = 0; r < 16; ++r) acc[r] = 0.0f;
#pragma unroll
    for (int kc = 0; kc < 16; ++kc) {
      float4 yv = yy[kc];
#pragma unroll
      for (int r = 0; r < 16; ++r) {
        const float4* xb = reinterpret_cast<const float4*>(x + (size_t)(r0 + r) * D);
        float4 xv = xb[kc];
        acc[r] = fmaf(xv.x, yv.x, acc[r]);
        acc[r] = fmaf(xv.y, yv.y, acc[r]);
        acc[r] = fmaf(xv.z, yv.z, acc[r]);
        acc[r] = fmaf(xv.w, yv.w, acc[r]);
      }
    }
    u64 cpart = s_colPart[c];
#pragma unroll
    for (int r = 0; r < 16; ++r) {
      float t = __fadd_rn(x2r[r], y2j);
      float sq = __fsub_rn(t, __fmul_rn(2.0f, acc[r]));
      sq = fmaxf(sq, 0.0f);
      float cost = __fsqrt_rn(sq);
      g_C[(size_t)(r0 + r) * N + j] = cost;
      u64 cb = ((u64)__float_as_uint(cost)) << 32;
      u64 rk = cb | (unsigned)j;
      best[r] = (rk < best[r]) ? rk : best[r];
      u64 ck = cb | (unsigned)(r0 + r);
      cpart = (ck < cpart) ? ck : cpart;
    }
    s_colPart[c] = cpart;
  }

  block_rowmin_reduce8(best, 16, s_part);
  if (tid < 16) g_rowBestJ[r0 + tid] = (int)(s_part[128 + tid] & 0xffffffffull);

  for (int c = tid; c < N; c += SNT) {
    u64 k = s_colPart[c];
    u64 curv = g_colMin[0][c];  // stale reads only ever too-high: safe filter
    if (k < curv) atomicMin((unsigned long long*)&g_colMin[0][c], k);
  }
}

// ================= rounds >= 1: gather scan over free rows/cols =================
__global__ void __launch_bounds__(SNT, 2) k_scanN(int round) {
  if (g_done) return;
  const int cur = round & 1;
  const int nr = g_nr[cur], nc = g_nc[cur];
  const int tid = threadIdx.x, bid = blockIdx.x;
  const int ngroups = (nr + 15) >> 4;
  if (bid >= ngroups) return;
  __shared__ u64 s_colPart[4096];
  __shared__ u64 s_part[128 + 16];
  __shared__ int s_irow[16];

  const int r0 = bid << 4;
  const int rows = min(16, nr - r0);
  if (tid < 16) {
    int rr = (tid < rows) ? (r0 + tid) : r0;
    s_irow[tid] = g_freeRows[cur][rr];
  }
  for (int c = tid; c < nc; c += SNT) s_colPart[c] = ~0ull;
  __syncthreads();

  int ir[16];
#pragma unroll
  for (int r = 0; r < 16; ++r) ir[r] = s_irow[r];
  u64 best[16];
#pragma unroll
  for (int r = 0; r < 16; ++r) best[r] = ~0ull;

  for (int c = tid; c < nc; c += SNT) {
    const int j = g_freeCols[cur][c];
    u64 cpart = s_colPart[c];
#pragma unroll
    for (int r = 0; r < 16; ++r) {
      if (r < rows) {
        float cost = g_C[(size_t)ir[r] * N + j];
        u64 cb = ((u64)__float_as_uint(cost)) << 32;
        u64 rk = cb | (unsigned)j;
        best[r] = (rk < best[r]) ? rk : best[r];
        u64 ck = cb | (unsigned)ir[r];
        cpart = (ck < cpart) ? ck : cpart;
      }
    }
    s_colPart[c] = cpart;
  }

  block_rowmin_reduce8(best, rows, s_part);
  if (tid < rows) g_rowBestJ[s_irow[tid]] = (int)(s_part[128 + tid] & 0xffffffffull);

  for (int c = tid; c < nc; c += SNT) {
    u64 k = s_colPart[c];
    if (k != ~0ull) {
      int j = g_freeCols[cur][c];
      u64 curv = g_colMin[cur][j];
      if (k < curv) atomicMin((unsigned long long*)&g_colMin[cur][j], k);
    }
  }
}

// ================= match + rebuild free lists =================
__global__ void __launch_bounds__(SNT) k_match(int round) {
  if (g_done) return;
  const int cur = round & 1, nxt = cur ^ 1;
  const int tid = threadIdx.x, bid = blockIdx.x;
  const int nr = g_nr[cur], nc = g_nc[cur];
  __shared__ int s_wc[8];
  __shared__ int s_base;

  if (bid >= 2) {  // reset colMin buffer for round+1
    for (int t = (bid - 2) * SNT + tid; t < N; t += (SNB - 2) * SNT)
      g_colMin[nxt][t] = ~0ull;
    return;
  }

  const int lane = tid & 63, wv = tid >> 6;
  if (bid == 0) {  // rows: write matches + ordered compaction
    if (tid == 0) s_base = 0;
    __syncthreads();
    for (int start = 0; start < nr; start += SNT) {
      int r = start + tid;
      int keep = 0; int iv = -1;
      if (r < nr) {
        int i = g_freeRows[cur][r];
        iv = i;
        int j = g_rowBestJ[i];
        u64 cm = g_colMin[cur][j];
        if ((int)(unsigned)(cm & 0xffffffffull) == i) g_rowMatch[i] = j;
        else keep = 1;
      }
      u64 bm = __ballot(keep);
      int pre = __popcll(bm & ((1ull << lane) - 1ull));
      if (lane == 0) s_wc[wv] = __popcll(bm);
      __syncthreads();
      int off = 0, tot = 0;
#pragma unroll
      for (int w = 0; w < 8; ++w) { off += (w < wv) ? s_wc[w] : 0; tot += s_wc[w]; }
      if (keep) g_freeRows[nxt][s_base + off + pre] = iv;
      __syncthreads();
      if (tid == 0) s_base += tot;
      __syncthreads();
    }
    if (tid == 0) {
      int nnr = s_base;
      g_nr[nxt] = nnr;
      if (nnr <= TCAP || nnr >= nr) { g_finalCur = nxt; g_done = 1; }
    }
  } else {  // cols
    if (tid == 0) s_base = 0;
    __syncthreads();
    for (int start = 0; start < nc; start += SNT) {
      int c = start + tid;
      int keep = 0; int jv = -1;
      if (c < nc) {
        int j = g_freeCols[cur][c];
        jv = j;
        u64 cm = g_colMin[cur][j];
        int i2 = (int)(unsigned)(cm & 0xffffffffull);
        if (g_rowBestJ[i2] != j) keep = 1;
      }
      u64 bm = __ballot(keep);
      int pre = __popcll(bm & ((1ull << lane) - 1ull));
      if (lane == 0) s_wc[wv] = __popcll(bm);
      __syncthreads();
      int off = 0, tot = 0;
#pragma unroll
      for (int w = 0; w < 8; ++w) { off += (w < wv) ? s_wc[w] : 0; tot += s_wc[w]; }
      if (keep) g_freeCols[nxt][s_base + off + pre] = jv;
      __syncthreads();
      if (tid == 0) s_base += tot;
      __syncthreads();
    }
    if (tid == 0) g_nc[nxt] = s_base;
  }
}

// ================= gather dense tail submatrix (whole grid) =================
// Tolerant: runs off g_finalCur (fallback parity if g_done never fired).
__global__ void __launch_bounds__(SNT) k_gather() {
  const int fc = g_finalCur;
  const int mr = g_nr[fc], mc = g_nc[fc];
  if (mr <= 0 || mr > TCAP || mc <= 0 || mc > TCAP) return;
  const int tid = threadIdx.x, bid = blockIdx.x;
  for (int rr = bid; rr < mr; rr += SNB) {
    const int irow = g_freeRows[fc][rr];
    const float* src = g_C + (size_t)irow * N;
    float* dst = g_tailC + (size_t)rr * TCAP;
    for (int c = tid; c < mc; c += SNT) {
      dst[c] = src[g_freeCols[fc][c]];
    }
  }
}

// ================= tail: one block, dense matrix, per-wave rows =================
__global__ void __launch_bounds__(1024, 1) k_tail(int* __restrict__ out) {
  __shared__ int s_rpos[2][TCAP], s_cpos[2][TCAP];
  __shared__ int s_rbest[TCAP];
  __shared__ u64 s_cmin[TCAP];
  __shared__ int s_wc[16];
  const int tid = threadIdx.x;
  const int lane = tid & 63, wv = tid >> 6;

  const int fc = g_finalCur;
  int mr = g_nr[fc], mc = g_nc[fc];
  if (mr < 0 || mr > TCAP || mc < 0 || mc > TCAP) mr = 0;  // bail loudly (validation fails)
  for (int t = tid; t < mr; t += 1024) s_rpos[0][t] = t;
  for (int t = tid; t < mc; t += 1024) s_cpos[0][t] = t;
  __syncthreads();

  int tcur = 0;
  for (int round = 0; round < 2048 && mr > 0; ++round) {
    // ---- phase A: row bests, one row per wave ----
    const int nit = (mc + 63) >> 6;
    int cpv[16];
#pragma unroll
    for (int k = 0; k < 16; ++k) {
      int ci = (k << 6) + lane;
      cpv[k] = (k < nit && ci < mc) ? s_cpos[tcur][ci] : 0;
    }
    for (int rr = wv; rr < mr; rr += 16) {
      const int rp = s_rpos[tcur][rr];
      const float* rowp = g_tailC + (size_t)rp * TCAP;
      u64 best = ~0ull;
#pragma unroll
      for (int k = 0; k < 16; ++k) {
        if (k < nit) {
          int ci = (k << 6) + lane;
          if (ci < mc) {
            float cost = rowp[cpv[k]];
            u64 key = (((u64)__float_as_uint(cost)) << 32) | (unsigned)ci;  // col position
            best = (key < best) ? key : best;
          }
        }
      }
#pragma unroll
      for (int d = 32; d > 0; d >>= 1) {
        u64 o = shfl_down_u64(best, d);
        best = (o < best) ? o : best;
      }
      if (lane == 0) s_rbest[rr] = (int)(best & 0xffffffffull);
    }
    __syncthreads();
    // ---- phase B: col mins, one col per thread (mc <= 1024 = blockDim) ----
    if (tid < mc) {
      const int cp = s_cpos[tcur][tid];
      const float* colp = g_tailC + cp;
      u64 best = ~0ull;
      int r = 0;
      for (; r + 4 <= mr; r += 4) {
#pragma unroll
        for (int q = 0; q < 4; ++q) {
          int rp = s_rpos[tcur][r + q];
          float cost = colp[(size_t)rp * TCAP];
          u64 key = (((u64)__float_as_uint(cost)) << 32) | (unsigned)(r + q);  // row position
          best = (key < best) ? key : best;
        }
      }
      for (; r < mr; ++r) {
        int rp = s_rpos[tcur][r];
        float cost = colp[(size_t)rp * TCAP];
        u64 key = (((u64)__float_as_uint(cost)) << 32) | (unsigned)r;
        best = (key < best) ? key : best;
      }
      s_cmin[tid] = best;
    }
    __syncthreads();
    // ---- match rows + compact ----
    int keep = 0;
    if (tid < mr) {
      int q = s_rbest[tid];
      if ((int)(unsigned)(s_cmin[q] & 0xffffffffull) == tid) {
        g_rowMatch[g_freeRows[fc][s_rpos[tcur][tid]]] = g_freeCols[fc][s_cpos[tcur][q]];
      } else keep = 1;
    }
    u64 bm = __ballot(keep);
    int pre = __popcll(bm & ((1ull << lane) - 1ull));
    if (lane == 0) s_wc[wv] = __popcll(bm);
    __syncthreads();
    int off = 0, tot = 0;
#pragma unroll
    for (int w = 0; w < 16; ++w) { off += (w < wv) ? s_wc[w] : 0; tot += s_wc[w]; }
    if (keep) s_rpos[tcur ^ 1][off + pre] = s_rpos[tcur][tid];
    int newmr = tot;
    __syncthreads();
    // ---- compact cols ----
    int keepc = 0;
    if (tid < mc) {
      int r2 = (int)(unsigned)(s_cmin[tid] & 0xffffffffull);
      if (s_rbest[r2] != tid) keepc = 1;
    }
    u64 bm2 = __ballot(keepc);
    int pre2 = __popcll(bm2 & ((1ull << lane) - 1ull));
    if (lane == 0) s_wc[wv] = __popcll(bm2);
    __syncthreads();
    int off2 = 0, tot2 = 0;
#pragma unroll
    for (int w = 0; w < 16; ++w) { off2 += (w < wv) ? s_wc[w] : 0; tot2 += s_wc[w]; }
    if (keepc) s_cpos[tcur ^ 1][off2 + pre2] = s_cpos[tcur][tid];
    __syncthreads();
    if (newmr >= mr) break;  // safety (cannot happen mathematically)
    mr = newmr; mc = tot2; tcur ^= 1;
  }
  __syncthreads();
  for (int i = tid; i < N; i += 1024) out[i] = g_rowMatch[i];
}

extern "C" void kernel_launch(void* const* d_in, const int* in_sizes, int n_in,
                              void* d_out, int out_size, void* d_ws, size_t ws_size,
                              hipStream_t stream) {
  const float* x = (const float*)d_in[0];
  const float* y = (const float*)d_in[1];
  int* out = (int*)d_out;
  k_init<<<16, 256, 0, stream>>>(x, y);
  k_scan0<<<SNB, SNT, 0, stream>>>(x, y);
  k_match<<<SNB, SNT, 0, stream>>>(0);
  for (int r = 1; r <= RPAIRS; ++r) {
    k_scanN<<<SNB, SNT, 0, stream>>>(r);
    k_match<<<SNB, SNT, 0, stream>>>(r);
  }
  k_gather<<<SNB, SNT, 0, stream>>>();
  k_tail<<<1, 1024, 0, stream>>>(out);
  (void)in_sizes; (void)n_in; (void)out_size; (void)d_ws; (void)ws_size;
}

// Round 5
// 897.592 us; speedup vs baseline: 2.3713x; 1.8162x over previous
//
#include <hip/hip_runtime.h>

#define N 4096
#define D 64
#define TCAP 1024
#define TTHRESH 96
#define SNB 256
#define SNT 512
#define RPAIRS 14

typedef unsigned long long u64;

// ---- persistent device state ----
__device__ float g_C[(size_t)N * (size_t)N];   // 64 MB cost matrix
__device__ float g_tailC[(size_t)TCAP * TCAP]; // 4 MB dense tail matrix
__device__ float g_x2[N], g_y2[N];
__device__ int   g_rowMatch[N];
__device__ int   g_freeRows[2][N];
__device__ int   g_freeCols[2][N];
__device__ int   g_rowBestJ[N];
__device__ u64   g_colMin[2][N];
__device__ int   g_nr[2], g_nc[2];
__device__ int   g_done, g_finalCur;

__device__ inline u64 shfl_down_u64(u64 v, int d) {
  unsigned lo = (unsigned)(v & 0xffffffffull);
  unsigned hi = (unsigned)(v >> 32);
  lo = __shfl_down(lo, d, 64);
  hi = __shfl_down(hi, d, 64);
  return ((u64)hi << 32) | (u64)lo;
}

// 512-thread (8-wave) block min-reduce of per-thread best[r], r < rows <= 16.
// Result for row r in s_part[128 + r].
__device__ inline void block_rowmin_reduce8(u64* best, int rows, u64* s_part) {
  const int tid = threadIdx.x;
  const int lane = tid & 63;
  const int wv = tid >> 6;
#pragma unroll
  for (int r = 0; r < 16; ++r) {
    if (r < rows) {
      u64 v = best[r];
#pragma unroll
      for (int d = 32; d > 0; d >>= 1) {
        u64 o = shfl_down_u64(v, d);
        v = (o < v) ? o : v;
      }
      if (lane == 0) s_part[r * 8 + wv] = v;
    }
  }
  __syncthreads();
  if (tid < rows) {
    u64 mn = s_part[tid * 8];
#pragma unroll
    for (int w = 1; w < 8; ++w) {
      u64 o = s_part[tid * 8 + w];
      mn = (o < mn) ? o : mn;
    }
    s_part[128 + tid] = mn;
  }
}

// ================= init: x2/y2 + state reset =================
__global__ void __launch_bounds__(256) k_init(const float* __restrict__ x,
                                              const float* __restrict__ y) {
  const int i = blockIdx.x * 256 + threadIdx.x;  // grid = 16 blocks -> 4096
  // numpy pairwise_sum order for n=64: 8 accumulators, then
  // ((r0+r1)+(r2+r3)) + ((r4+r5)+(r6+r7)). No FMA contraction.
  const float* xr = x + (size_t)i * D;
  const float* yr = y + (size_t)i * D;
  float qx[8], qy[8];
#pragma unroll
  for (int j = 0; j < 8; ++j) {
    float v = xr[j]; qx[j] = __fmul_rn(v, v);
    float w = yr[j]; qy[j] = __fmul_rn(w, w);
  }
#pragma unroll
  for (int m = 8; m < D; m += 8) {
#pragma unroll
    for (int j = 0; j < 8; ++j) {
      float v = xr[m + j]; qx[j] = __fadd_rn(qx[j], __fmul_rn(v, v));
      float w = yr[m + j]; qy[j] = __fadd_rn(qy[j], __fmul_rn(w, w));
    }
  }
  g_x2[i] = __fadd_rn(__fadd_rn(__fadd_rn(qx[0], qx[1]), __fadd_rn(qx[2], qx[3])),
                      __fadd_rn(__fadd_rn(qx[4], qx[5]), __fadd_rn(qx[6], qx[7])));
  g_y2[i] = __fadd_rn(__fadd_rn(__fadd_rn(qy[0], qy[1]), __fadd_rn(qy[2], qy[3])),
                      __fadd_rn(__fadd_rn(qy[4], qy[5]), __fadd_rn(qy[6], qy[7])));
  g_rowMatch[i] = -1;
  g_freeRows[0][i] = i;
  g_freeCols[0][i] = i;
  g_colMin[0][i] = ~0ull;
  g_colMin[1][i] = ~0ull;
  if (i == 0) {
    g_nr[0] = N; g_nc[0] = N; g_nr[1] = 0; g_nc[1] = 0;
    g_done = 0;
    g_finalCur = ((RPAIRS & 1) ^ 1);  // fallback parity if g_done never fires
  }
}

// ================= round 0: fused cost + C store + row/col minima =================
// Register-tiled: 16 rows x 4 cols per thread, 2 column passes.
// Per-(r,c) fmaf chain order identical to previous (kc ascending, x/y/z/w).
__global__ void __launch_bounds__(SNT) k_scan0(const float* __restrict__ x,
                                               const float* __restrict__ y) {
  __shared__ u64 s_part[128 + 16];
  const int tid = threadIdx.x;
  const int r0 = blockIdx.x << 4;  // 256 blocks x 16 rows

  float x2r[16];
#pragma unroll
  for (int r = 0; r < 16; ++r) x2r[r] = g_x2[r0 + r];
  u64 best[16];
#pragma unroll
  for (int r = 0; r < 16; ++r) best[r] = ~0ull;

#pragma unroll
  for (int q = 0; q < 2; ++q) {
    const int c0 = tid + (q << 11);  // cols c0 + 512*k, k=0..3
    float acc[16][4];
#pragma unroll
    for (int r = 0; r < 16; ++r)
#pragma unroll
      for (int k = 0; k < 4; ++k) acc[r][k] = 0.0f;

    const float4* yb0 = reinterpret_cast<const float4*>(y + (size_t)c0 * D);
    const float4* yb1 = reinterpret_cast<const float4*>(y + (size_t)(c0 + 512) * D);
    const float4* yb2 = reinterpret_cast<const float4*>(y + (size_t)(c0 + 1024) * D);
    const float4* yb3 = reinterpret_cast<const float4*>(y + (size_t)(c0 + 1536) * D);
#pragma unroll
    for (int kc = 0; kc < 16; ++kc) {
      float4 yv0 = yb0[kc], yv1 = yb1[kc], yv2 = yb2[kc], yv3 = yb3[kc];
#pragma unroll
      for (int r = 0; r < 16; ++r) {
        float4 xv = reinterpret_cast<const float4*>(x + (size_t)(r0 + r) * D)[kc];  // wave-uniform
        acc[r][0] = fmaf(xv.x, yv0.x, acc[r][0]);
        acc[r][0] = fmaf(xv.y, yv0.y, acc[r][0]);
        acc[r][0] = fmaf(xv.z, yv0.z, acc[r][0]);
        acc[r][0] = fmaf(xv.w, yv0.w, acc[r][0]);
        acc[r][1] = fmaf(xv.x, yv1.x, acc[r][1]);
        acc[r][1] = fmaf(xv.y, yv1.y, acc[r][1]);
        acc[r][1] = fmaf(xv.z, yv1.z, acc[r][1]);
        acc[r][1] = fmaf(xv.w, yv1.w, acc[r][1]);
        acc[r][2] = fmaf(xv.x, yv2.x, acc[r][2]);
        acc[r][2] = fmaf(xv.y, yv2.y, acc[r][2]);
        acc[r][2] = fmaf(xv.z, yv2.z, acc[r][2]);
        acc[r][2] = fmaf(xv.w, yv2.w, acc[r][2]);
        acc[r][3] = fmaf(xv.x, yv3.x, acc[r][3]);
        acc[r][3] = fmaf(xv.y, yv3.y, acc[r][3]);
        acc[r][3] = fmaf(xv.z, yv3.z, acc[r][3]);
        acc[r][3] = fmaf(xv.w, yv3.w, acc[r][3]);
      }
    }
#pragma unroll
    for (int k = 0; k < 4; ++k) {
      const int c = c0 + (k << 9);
      const float y2j = g_y2[c];
      u64 ckey = ~0ull;
#pragma unroll
      for (int r = 0; r < 16; ++r) {
        float t = __fadd_rn(x2r[r], y2j);
        float sq = __fsub_rn(t, __fmul_rn(2.0f, acc[r][k]));
        sq = fmaxf(sq, 0.0f);
        float cost = __fsqrt_rn(sq);
        g_C[(size_t)(r0 + r) * N + c] = cost;
        u64 cb = ((u64)__float_as_uint(cost)) << 32;
        u64 rk = cb | (unsigned)c;
        best[r] = (rk < best[r]) ? rk : best[r];
        u64 ck = cb | (unsigned)(r0 + r);
        ckey = (ck < ckey) ? ck : ckey;
      }
      u64 curv = g_colMin[0][c];  // stale reads only ever too-high: safe filter
      if (ckey < curv) atomicMin((unsigned long long*)&g_colMin[0][c], ckey);
    }
  }

  block_rowmin_reduce8(best, 16, s_part);
  if (tid < 16) g_rowBestJ[r0 + tid] = (int)(s_part[128 + tid] & 0xffffffffull);
}

// ================= rounds >= 1: gather scan over free rows/cols =================
__global__ void __launch_bounds__(SNT, 2) k_scanN(int round) {
  if (g_done) return;
  const int cur = round & 1;
  const int nr = g_nr[cur], nc = g_nc[cur];
  const int tid = threadIdx.x, bid = blockIdx.x;
  const int ngroups = (nr + 15) >> 4;
  if (bid >= ngroups) return;
  __shared__ u64 s_colPart[4096];
  __shared__ u64 s_part[128 + 16];
  __shared__ int s_irow[16];

  const int r0 = bid << 4;
  const int rows = min(16, nr - r0);
  if (tid < 16) {
    int rr = (tid < rows) ? (r0 + tid) : r0;
    s_irow[tid] = g_freeRows[cur][rr];
  }
  for (int c = tid; c < nc; c += SNT) s_colPart[c] = ~0ull;
  __syncthreads();

  int ir[16];
#pragma unroll
  for (int r = 0; r < 16; ++r) ir[r] = s_irow[r];
  u64 best[16];
#pragma unroll
  for (int r = 0; r < 16; ++r) best[r] = ~0ull;

  for (int c = tid; c < nc; c += SNT) {
    const int j = g_freeCols[cur][c];
    u64 cpart = s_colPart[c];
#pragma unroll
    for (int r = 0; r < 16; ++r) {
      if (r < rows) {
        float cost = g_C[(size_t)ir[r] * N + j];
        u64 cb = ((u64)__float_as_uint(cost)) << 32;
        u64 rk = cb | (unsigned)j;
        best[r] = (rk < best[r]) ? rk : best[r];
        u64 ck = cb | (unsigned)ir[r];
        cpart = (ck < cpart) ? ck : cpart;
      }
    }
    s_colPart[c] = cpart;
  }

  block_rowmin_reduce8(best, rows, s_part);
  if (tid < rows) g_rowBestJ[s_irow[tid]] = (int)(s_part[128 + tid] & 0xffffffffull);

  for (int c = tid; c < nc; c += SNT) {
    u64 k = s_colPart[c];
    if (k != ~0ull) {
      int j = g_freeCols[cur][c];
      u64 curv = g_colMin[cur][j];
      if (k < curv) atomicMin((unsigned long long*)&g_colMin[cur][j], k);
    }
  }
}

// ================= match + rebuild free lists =================
__global__ void __launch_bounds__(SNT) k_match(int round) {
  if (g_done) return;
  const int cur = round & 1, nxt = cur ^ 1;
  const int tid = threadIdx.x, bid = blockIdx.x;
  const int nr = g_nr[cur], nc = g_nc[cur];
  __shared__ int s_wc[8];
  __shared__ int s_base;

  if (bid >= 2) {  // reset colMin buffer for round+1
    for (int t = (bid - 2) * SNT + tid; t < N; t += (SNB - 2) * SNT)
      g_colMin[nxt][t] = ~0ull;
    return;
  }

  const int lane = tid & 63, wv = tid >> 6;
  if (bid == 0) {  // rows: write matches + ordered compaction
    if (tid == 0) s_base = 0;
    __syncthreads();
    for (int start = 0; start < nr; start += SNT) {
      int r = start + tid;
      int keep = 0; int iv = -1;
      if (r < nr) {
        int i = g_freeRows[cur][r];
        iv = i;
        int j = g_rowBestJ[i];
        u64 cm = g_colMin[cur][j];
        if ((int)(unsigned)(cm & 0xffffffffull) == i) g_rowMatch[i] = j;
        else keep = 1;
      }
      u64 bm = __ballot(keep);
      int pre = __popcll(bm & ((1ull << lane) - 1ull));
      if (lane == 0) s_wc[wv] = __popcll(bm);
      __syncthreads();
      int off = 0, tot = 0;
#pragma unroll
      for (int w = 0; w < 8; ++w) { off += (w < wv) ? s_wc[w] : 0; tot += s_wc[w]; }
      if (keep) g_freeRows[nxt][s_base + off + pre] = iv;
      __syncthreads();
      if (tid == 0) s_base += tot;
      __syncthreads();
    }
    if (tid == 0) {
      int nnr = s_base;
      g_nr[nxt] = nnr;
      if (nnr <= TTHRESH || nnr >= nr) { g_finalCur = nxt; g_done = 1; }
    }
  } else {  // cols
    if (tid == 0) s_base = 0;
    __syncthreads();
    for (int start = 0; start < nc; start += SNT) {
      int c = start + tid;
      int keep = 0; int jv = -1;
      if (c < nc) {
        int j = g_freeCols[cur][c];
        jv = j;
        u64 cm = g_colMin[cur][j];
        int i2 = (int)(unsigned)(cm & 0xffffffffull);
        if (g_rowBestJ[i2] != j) keep = 1;
      }
      u64 bm = __ballot(keep);
      int pre = __popcll(bm & ((1ull << lane) - 1ull));
      if (lane == 0) s_wc[wv] = __popcll(bm);
      __syncthreads();
      int off = 0, tot = 0;
#pragma unroll
      for (int w = 0; w < 8; ++w) { off += (w < wv) ? s_wc[w] : 0; tot += s_wc[w]; }
      if (keep) g_freeCols[nxt][s_base + off + pre] = jv;
      __syncthreads();
      if (tid == 0) s_base += tot;
      __syncthreads();
    }
    if (tid == 0) g_nc[nxt] = s_base;
  }
}

// ================= gather dense tail submatrix (whole grid) =================
// Tolerant: runs off g_finalCur (fallback parity if g_done never fired).
__global__ void __launch_bounds__(SNT) k_gather() {
  const int fc = g_finalCur;
  const int mr = g_nr[fc], mc = g_nc[fc];
  if (mr <= 0 || mr > TCAP || mc <= 0 || mc > TCAP) return;
  const int tid = threadIdx.x, bid = blockIdx.x;
  for (int rr = bid; rr < mr; rr += SNB) {
    const int irow = g_freeRows[fc][rr];
    const float* src = g_C + (size_t)irow * N;
    float* dst = g_tailC + (size_t)rr * TCAP;
    for (int c = tid; c < mc; c += SNT) {
      dst[c] = src[g_freeCols[fc][c]];
    }
  }
}

// ================= tail: one block, dense matrix, per-wave rows =================
__global__ void __launch_bounds__(1024, 1) k_tail(int* __restrict__ out) {
  __shared__ int s_rpos[2][TCAP], s_cpos[2][TCAP];
  __shared__ int s_rbest[TCAP];
  __shared__ u64 s_cmin[TCAP];
  __shared__ int s_wc[16];
  const int tid = threadIdx.x;
  const int lane = tid & 63, wv = tid >> 6;

  const int fc = g_finalCur;
  int mr = g_nr[fc], mc = g_nc[fc];
  if (mr < 0 || mr > TCAP || mc < 0 || mc > TCAP) mr = 0;  // bail loudly (validation fails)
  for (int t = tid; t < mr; t += 1024) s_rpos[0][t] = t;
  for (int t = tid; t < mc; t += 1024) s_cpos[0][t] = t;
  __syncthreads();

  int tcur = 0;
  for (int round = 0; round < 2048 && mr > 0; ++round) {
    // ---- phase A: row bests, one row per wave ----
    const int nit = (mc + 63) >> 6;
    int cpv[16];
#pragma unroll
    for (int k = 0; k < 16; ++k) {
      int ci = (k << 6) + lane;
      cpv[k] = (k < nit && ci < mc) ? s_cpos[tcur][ci] : 0;
    }
    for (int rr = wv; rr < mr; rr += 16) {
      const int rp = s_rpos[tcur][rr];
      const float* rowp = g_tailC + (size_t)rp * TCAP;
      u64 best = ~0ull;
#pragma unroll
      for (int k = 0; k < 16; ++k) {
        if (k < nit) {
          int ci = (k << 6) + lane;
          if (ci < mc) {
            float cost = rowp[cpv[k]];
            u64 key = (((u64)__float_as_uint(cost)) << 32) | (unsigned)ci;  // col position
            best = (key < best) ? key : best;
          }
        }
      }
#pragma unroll
      for (int d = 32; d > 0; d >>= 1) {
        u64 o = shfl_down_u64(best, d);
        best = (o < best) ? o : best;
      }
      if (lane == 0) s_rbest[rr] = (int)(best & 0xffffffffull);
    }
    __syncthreads();
    // ---- phase B: col mins, one col per thread (mc <= 1024 = blockDim) ----
    if (tid < mc) {
      const int cp = s_cpos[tcur][tid];
      const float* colp = g_tailC + cp;
      u64 best = ~0ull;
      int r = 0;
      for (; r + 4 <= mr; r += 4) {
#pragma unroll
        for (int q = 0; q < 4; ++q) {
          int rp = s_rpos[tcur][r + q];
          float cost = colp[(size_t)rp * TCAP];
          u64 key = (((u64)__float_as_uint(cost)) << 32) | (unsigned)(r + q);  // row position
          best = (key < best) ? key : best;
        }
      }
      for (; r < mr; ++r) {
        int rp = s_rpos[tcur][r];
        float cost = colp[(size_t)rp * TCAP];
        u64 key = (((u64)__float_as_uint(cost)) << 32) | (unsigned)r;
        best = (key < best) ? key : best;
      }
      s_cmin[tid] = best;
    }
    __syncthreads();
    // ---- match rows + compact ----
    int keep = 0;
    if (tid < mr) {
      int q = s_rbest[tid];
      if ((int)(unsigned)(s_cmin[q] & 0xffffffffull) == tid) {
        g_rowMatch[g_freeRows[fc][s_rpos[tcur][tid]]] = g_freeCols[fc][s_cpos[tcur][q]];
      } else keep = 1;
    }
    u64 bm = __ballot(keep);
    int pre = __popcll(bm & ((1ull << lane) - 1ull));
    if (lane == 0) s_wc[wv] = __popcll(bm);
    __syncthreads();
    int off = 0, tot = 0;
#pragma unroll
    for (int w = 0; w < 16; ++w) { off += (w < wv) ? s_wc[w] : 0; tot += s_wc[w]; }
    if (keep) s_rpos[tcur ^ 1][off + pre] = s_rpos[tcur][tid];
    int newmr = tot;
    __syncthreads();
    // ---- compact cols ----
    int keepc = 0;
    if (tid < mc) {
      int r2 = (int)(unsigned)(s_cmin[tid] & 0xffffffffull);
      if (s_rbest[r2] != tid) keepc = 1;
    }
    u64 bm2 = __ballot(keepc);
    int pre2 = __popcll(bm2 & ((1ull << lane) - 1ull));
    if (lane == 0) s_wc[wv] = __popcll(bm2);
    __syncthreads();
    int off2 = 0, tot2 = 0;
#pragma unroll
    for (int w = 0; w < 16; ++w) { off2 += (w < wv) ? s_wc[w] : 0; tot2 += s_wc[w]; }
    if (keepc) s_cpos[tcur ^ 1][off2 + pre2] = s_cpos[tcur][tid];
    __syncthreads();
    if (newmr >= mr) break;  // safety (cannot happen mathematically)
    mr = newmr; mc = tot2; tcur ^= 1;
  }
  __syncthreads();
  for (int i = tid; i < N; i += 1024) out[i] = g_rowMatch[i];
}

extern "C" void kernel_launch(void* const* d_in, const int* in_sizes, int n_in,
                              void* d_out, int out_size, void* d_ws, size_t ws_size,
                              hipStream_t stream) {
  const float* x = (const float*)d_in[0];
  const float* y = (const float*)d_in[1];
  int* out = (int*)d_out;
  k_init<<<16, 256, 0, stream>>>(x, y);
  k_scan0<<<SNB, SNT, 0, stream>>>(x, y);
  k_match<<<SNB, SNT, 0, stream>>>(0);
  for (int r = 1; r <= RPAIRS; ++r) {
    k_scanN<<<SNB, SNT, 0, stream>>>(r);
    k_match<<<SNB, SNT, 0, stream>>>(r);
  }
  k_gather<<<SNB, SNT, 0, stream>>>();
  k_tail<<<1, 1024, 0, stream>>>(out);
  (void)in_sizes; (void)n_in; (void)out_size; (void)d_ws; (void)ws_size;
}